// Round 5
// baseline (266.606 us; speedup 1.0000x reference)
//
#include <hip/hip_runtime.h>
#include <hip/hip_bf16.h>

typedef __bf16 bf16_t;
typedef __bf16 bf16x4 __attribute__((ext_vector_type(4)));
typedef __bf16 bf16x8 __attribute__((ext_vector_type(8)));
typedef float f32x4 __attribute__((ext_vector_type(4)));

#define MFMA16(a, b, c) __builtin_amdgcn_mfma_f32_16x16x32_bf16(a, b, c, 0, 0, 0)

// async 16B global->LDS (m97 pattern). lds ptr wave-uniform; lane writes
// ldsbase + lane*16.
__device__ __forceinline__ void gld16(const bf16_t* g, bf16_t* l) {
  __builtin_amdgcn_global_load_lds(
      (const __attribute__((address_space(1))) unsigned int*)(const void*)g,
      (__attribute__((address_space(3))) unsigned int*)(void*)l, 16, 0, 0);
}

// ---------------------------------------------------------------------------
// f32 -> bf16 elementwise convert (n multiple of 8)
// ---------------------------------------------------------------------------
__global__ __launch_bounds__(256) void cvt_f32_bf16(
    const float* __restrict__ src, bf16_t* __restrict__ dst, long long n) {
  long long i = ((long long)blockIdx.x * 256 + threadIdx.x) * 8;
  const long long stride = (long long)gridDim.x * 256 * 8;
  for (; i < n; i += stride) {
    f32x4 a = *(const f32x4*)(src + i);
    f32x4 b = *(const f32x4*)(src + i + 4);
    bf16x8 r;
#pragma unroll
    for (int e = 0; e < 4; ++e) {
      r[e] = (bf16_t)a[e];
      r[4 + e] = (bf16_t)b[e];
    }
    *(bf16x8*)(dst + i) = r;
  }
}

// ---------------------------------------------------------------------------
// GEMM: C[m][n] = sum_k A[m][k]*W[n][k] (+bias). A bf16 via global_load_lds.
// W: bf16 via global_load_lds (WF32=false) or f32 via reg-staging (true).
// 128x128 tile, 4 waves (2x2), 64x64/wave, BK=32, 2-phase double-buffer,
// __launch_bounds__(256,3), T1 XCD swizzle. (Unchanged this round; next
// structural step is the 8-phase counted-vmcnt port.)
// ---------------------------------------------------------------------------
template <bool WF32, typename TC, bool BIAS>
__global__ __launch_bounds__(256, 3) void gemm_async(
    const bf16_t* __restrict__ A, int lda, const void* __restrict__ Wv,
    const float* __restrict__ bias, TC* __restrict__ C, int ldc,
    int M, int N, int K) {
  constexpr int BST = WF32 ? 40 : 32;
  __shared__ bf16_t As[2][128 * 32];   // unpadded: global_load_lds layout
  __shared__ bf16_t Bs[2][128 * BST];

  const int tid = threadIdx.x;
  const int i = tid & 63;
  const int w = tid >> 6;
  const int l16 = tid & 15;
  const int quad = (tid >> 4) & 3;
  const int wm = w & 1;
  const int wn = w >> 1;

  // T1: bijective XCD swizzle (requires nwg % 8 == 0; both grids satisfy)
  const int nwg = gridDim.x * gridDim.y;
  int wg = blockIdx.y * gridDim.x + blockIdx.x;
  if ((nwg & 7) == 0) wg = (wg & 7) * (nwg >> 3) + (wg >> 3);
  const int m0 = (wg / gridDim.x) * 128;
  const int n0 = (wg % gridDim.x) * 128;

  const bf16_t* ag = A + (size_t)(m0 + w * 32 + (i >> 2)) * lda + (i & 3) * 8;
  bf16_t* as0[2] = {&As[0][(w * 32) * 32], &As[1][(w * 32) * 32]};
  bf16_t* as1[2] = {&As[0][(w * 32 + 16) * 32], &As[1][(w * 32 + 16) * 32]};

  const bf16_t* bg = nullptr;
  bf16_t *bs0[2] = {nullptr, nullptr}, *bs1[2] = {nullptr, nullptr};
  const float* wfg = nullptr;
  bf16_t* bsw[2] = {nullptr, nullptr};
  if (!WF32) {
    bg = (const bf16_t*)Wv + (size_t)(n0 + w * 32 + (i >> 2)) * K + (i & 3) * 8;
    bs0[0] = &Bs[0][(w * 32) * 32];
    bs0[1] = &Bs[1][(w * 32) * 32];
    bs1[0] = &Bs[0][(w * 32 + 16) * 32];
    bs1[1] = &Bs[1][(w * 32 + 16) * 32];
  } else {
    const int srow = tid >> 1;
    const int scol = (tid & 1) * 16;
    wfg = (const float*)Wv + (size_t)(n0 + srow) * K + scol;
    bsw[0] = &Bs[0][srow * BST + scol];
    bsw[1] = &Bs[1][srow * BST + scol];
  }

  f32x4 acc[4][4] = {};

  // ---- prologue: stage K-tile 0 into buffer 0 ----
  gld16(ag, as0[0]);
  gld16(ag + 16 * lda, as1[0]);
  if (!WF32) {
    gld16(bg, bs0[0]);
    gld16(bg + 16 * K, bs1[0]);
  } else {
    f32x4 a = *(const f32x4*)(wfg);
    f32x4 b = *(const f32x4*)(wfg + 4);
    f32x4 c2 = *(const f32x4*)(wfg + 8);
    f32x4 d = *(const f32x4*)(wfg + 12);
    bf16x8 r0, r1;
#pragma unroll
    for (int e = 0; e < 4; ++e) {
      r0[e] = (bf16_t)a[e];
      r0[4 + e] = (bf16_t)b[e];
      r1[e] = (bf16_t)c2[e];
      r1[4 + e] = (bf16_t)d[e];
    }
    *(bf16x8*)(bsw[0]) = r0;
    *(bf16x8*)(bsw[0] + 8) = r1;
  }
  __syncthreads();  // implicit vmcnt(0): tile 0 resident

  int cur = 0;
  for (int k0 = 0; k0 < K; k0 += 32) {
    const bool has_next = (k0 + 32 < K);
    const int nxt = cur ^ 1;
    f32x4 wa, wb, wc, wd;  // WF32 staging regs (issued early, used late)

    // issue next tile's loads -> other buffer (in flight during compute)
    if (has_next) {
      gld16(ag + k0 + 32, as0[nxt]);
      gld16(ag + 16 * lda + k0 + 32, as1[nxt]);
      if (!WF32) {
        gld16(bg + k0 + 32, bs0[nxt]);
        gld16(bg + 16 * K + k0 + 32, bs1[nxt]);
      } else {
        wa = *(const f32x4*)(wfg + k0 + 32);
        wb = *(const f32x4*)(wfg + k0 + 36);
        wc = *(const f32x4*)(wfg + k0 + 40);
        wd = *(const f32x4*)(wfg + k0 + 44);
      }
    }

    // compute current tile
    bf16x8 af[4], bfr[4];
#pragma unroll
    for (int t = 0; t < 4; ++t) {
      af[t] = *(const bf16x8*)&As[cur][(wm * 64 + t * 16 + l16) * 32 + quad * 8];
      bfr[t] =
          *(const bf16x8*)&Bs[cur][(wn * 64 + t * 16 + l16) * BST + quad * 8];
    }
    __builtin_amdgcn_s_setprio(1);
#pragma unroll
    for (int mi = 0; mi < 4; ++mi)
#pragma unroll
      for (int ni = 0; ni < 4; ++ni)
        acc[mi][ni] = MFMA16(af[mi], bfr[ni], acc[mi][ni]);
    __builtin_amdgcn_s_setprio(0);

    // WF32: convert + commit staged regs (vmcnt waits here, after MFMA)
    if (WF32 && has_next) {
      bf16x8 r0, r1;
#pragma unroll
      for (int e = 0; e < 4; ++e) {
        r0[e] = (bf16_t)wa[e];
        r0[4 + e] = (bf16_t)wb[e];
        r1[e] = (bf16_t)wc[e];
        r1[4 + e] = (bf16_t)wd[e];
      }
      *(bf16x8*)(bsw[nxt]) = r0;
      *(bf16x8*)(bsw[nxt] + 8) = r1;
    }

    __syncthreads();  // drains vmcnt+lgkmcnt; next tile resident, cur free
    cur = nxt;
  }

#pragma unroll
  for (int ni = 0; ni < 4; ++ni) {
    const int col = n0 + wn * 64 + ni * 16 + l16;
    const float bv = BIAS ? bias[col] : 0.0f;
#pragma unroll
    for (int mi = 0; mi < 4; ++mi) {
      const int row = m0 + wm * 64 + mi * 16 + quad * 4;
#pragma unroll
      for (int r = 0; r < 4; ++r)
        C[(size_t)(row + r) * ldc + col] = (TC)(acc[mi][ni][r] + bv);
    }
  }
}

// ---------------------------------------------------------------------------
// Flash attention (causal), qkv interleaved [B*T, 3C] bf16 (q|k|v).
// Output overwrites the Q slot in place (R3-verified disjointness).
//
// v2: swapped QK^T (S^T = mfma(K,Q)); lane holds a full q-row slice.
// v3: exp2-domain softmax; diagonal-only causal mask; exact defer-skip;
//     setprio; T14 reg-staged K/V prefetch; single-buffer LDS (36.8 KB).
// v5 (this round): OCCUPANCY. One strip per block: grid (B*H=64, 16) =
//     1024 blocks -> 4 blocks/CU = 32 waves/CU (was 2 blocks/CU, Occ 38%).
//     LDS 36864B fits 4/CU (147 KB); VGPR 56 allows 8 waves/SIMD.
//     Balance without pairing: qt = (y<8) ? y : 23-y. Under mod-256
//     round-robin dispatch each CU's 4 blocks get strips {a, a+4, 15-a,
//     11-a} -> per-CU tile totals are EXACTLY equal (68 = mean); any other
//     dispatch still gets a well-mixed spread. Total loads unchanged.
// ---------------------------------------------------------------------------
__global__ __launch_bounds__(512, 4) void attn_mfma(bf16_t* __restrict__ qkv) {
  constexpr int T = 2048, C3 = 3072, C = 1024;
  __shared__ bf16_t Ks[64 * 72];      // [token][d], +8 pad
  __shared__ bf16_t Vt[64 * 72];      // [d][token], +8 pad
  __shared__ bf16_t Ps[8 * 16 * 72];  // per-wave P tile [qrow][key]

  const int tid = threadIdx.x;
  const int wave = tid >> 6;        // 0..7
  const int lane = tid & 63;
  const int l16 = tid & 15;
  const int quad = (tid >> 4) & 3;
  const int bh = blockIdx.x;        // 0..63
  const int b = bh >> 4;
  const int h = bh & 15;
  const int y = blockIdx.y;         // 0..15
  const int qt = (y < 8) ? y : 23 - y;  // bijection; balances per-CU work
  bf16_t* base = qkv + (size_t)b * T * C3;

  // 1/sqrt(64) * log2(e): softmax entirely in exp2 domain.
  const float QSCALE = 0.125f * 1.44269504088896340736f;

  // K staging map (waves 0-3): token = tid>>2 (0..63), 16 d's at (tid&3)*16
  const int kst = tid >> 2;
  const int ksd = (tid & 3) * 16;
  // V staging map (waves 4-7): token = lane, 16 d's at (wave-4)*16
  const int vtok = lane;
  const int vdg = (wave - 4) * 16;

  bf16_t* pw = &Ps[wave * 16 * 72];

  bf16x8 st0, st1;  // staging regs: K halves (waves 0-3) or V halves (4-7)

  const int Q0 = qt * 128;
  const int qlo = Q0 + wave * 16;
  const int jmax = Q0 + 64;

  // Q fragments, prescaled by 0.125*log2e (one extra bf16 rounding on Q)
  bf16x8 qf[2];
  {
    const bf16_t* qp = base + (size_t)(qlo + l16) * C3 + h * 64 + quad * 8;
    bf16x8 a = *(const bf16x8*)qp;
    bf16x8 c = *(const bf16x8*)(qp + 32);
#pragma unroll
    for (int e = 0; e < 8; ++e) {
      a[e] = (bf16_t)((float)a[e] * QSCALE);
      c[e] = (bf16_t)((float)c[e] * QSCALE);
    }
    qf[0] = a;
    qf[1] = c;
  }

  f32x4 Of[4] = {};
  float mrow = -1e30f;
  float lrow = 0.f;

  // prologue: issue tile-0 loads into regs (T14 split)
  if (wave < 4) {
    const bf16_t* kp = base + (size_t)kst * C3 + C + h * 64 + ksd;
    st0 = *(const bf16x8*)kp;
    st1 = *(const bf16x8*)(kp + 8);
  } else {
    const bf16_t* vp = base + (size_t)vtok * C3 + 2 * C + h * 64 + vdg;
    st0 = *(const bf16x8*)vp;
    st1 = *(const bf16x8*)(vp + 8);
  }

  for (int j0 = 0; j0 <= jmax; j0 += 64) {
    __syncthreads();  // previous tile's Ks/Vt readers are done
    // commit staged regs -> LDS (implicit vmcnt wait on st0/st1)
    if (wave < 4) {
      *(bf16x8*)&Ks[kst * 72 + ksd] = st0;
      *(bf16x8*)&Ks[kst * 72 + ksd + 8] = st1;
    } else {
#pragma unroll
      for (int e = 0; e < 8; ++e) {
        Vt[(vdg + e) * 72 + vtok] = st0[e];
        Vt[(vdg + 8 + e) * 72 + vtok] = st1[e];
      }
    }
    // issue next tile's loads; latency hides under compute below
    if (j0 + 64 <= jmax) {
      const int jn = j0 + 64;
      if (wave < 4) {
        const bf16_t* kp = base + (size_t)(jn + kst) * C3 + C + h * 64 + ksd;
        st0 = *(const bf16x8*)kp;
        st1 = *(const bf16x8*)(kp + 8);
      } else {
        const bf16_t* vp =
            base + (size_t)(jn + vtok) * C3 + 2 * C + h * 64 + vdg;
        st0 = *(const bf16x8*)vp;
        st1 = *(const bf16x8*)(vp + 8);
      }
    }
    __syncthreads();

    if (qlo + 15 < j0) continue;  // wave-uniform: fully-masked wave skips

    // S^T tile: lane holds S[qlo+l16][j0 + nt*16 + quad*4 + r]
    float Sv[4][4];
    const int qrow = qlo + l16;
    __builtin_amdgcn_s_setprio(1);
#pragma unroll
    for (int nt = 0; nt < 4; ++nt) {
      f32x4 sacc = {};
#pragma unroll
      for (int s2 = 0; s2 < 2; ++s2) {
        bf16x8 kf =
            *(const bf16x8*)&Ks[(nt * 16 + l16) * 72 + s2 * 32 + quad * 8];
        sacc = MFMA16(kf, qf[s2], sacc);  // swapped: rows=keys, cols=qrows
      }
#pragma unroll
      for (int r = 0; r < 4; ++r) Sv[nt][r] = sacc[r];
    }
    __builtin_amdgcn_s_setprio(0);

    // causal mask: only the diagonal-overlap tile needs it (wave-uniform)
    if (j0 + 64 > qlo) {
#pragma unroll
      for (int nt = 0; nt < 4; ++nt) {
        const int keyb = j0 + nt * 16 + quad * 4;
#pragma unroll
        for (int r = 0; r < 4; ++r)
          if (keyb + r > qrow) Sv[nt][r] = -1e30f;
      }
    }

    // tile max for this lane's row (tree, then cross-quad)
    float vm[4];
#pragma unroll
    for (int nt = 0; nt < 4; ++nt)
      vm[nt] = fmaxf(fmaxf(Sv[nt][0], Sv[nt][1]),
                     fmaxf(Sv[nt][2], Sv[nt][3]));
    float v = fmaxf(fmaxf(vm[0], vm[1]), fmaxf(vm[2], vm[3]));
    v = fmaxf(v, __shfl_xor(v, 16));
    v = fmaxf(v, __shfl_xor(v, 32));

    // exact defer-skip: when no row grew, alpha==1 exactly -> skip rescale
    if (__any(v > mrow)) {
      const float mnew = fmaxf(mrow, v);
      const float alpha = __builtin_amdgcn_exp2f(mrow - mnew);
      mrow = mnew;
      lrow *= alpha;
      float ar[4];
#pragma unroll
      for (int r = 0; r < 4; ++r) ar[r] = __shfl(alpha, quad * 4 + r, 16);
#pragma unroll
      for (int dt = 0; dt < 4; ++dt)
#pragma unroll
        for (int r = 0; r < 4; ++r) Of[dt][r] *= ar[r];
    }

    // P = exp2(S - m); pack 4 consecutive keys -> one ds_write_b64 per nt
    float rsn[4];
#pragma unroll
    for (int nt = 0; nt < 4; ++nt) {
      bf16x4 pk;
      float r0 = __builtin_amdgcn_exp2f(Sv[nt][0] - mrow);
      float r1 = __builtin_amdgcn_exp2f(Sv[nt][1] - mrow);
      float r2 = __builtin_amdgcn_exp2f(Sv[nt][2] - mrow);
      float r3 = __builtin_amdgcn_exp2f(Sv[nt][3] - mrow);
      pk[0] = (bf16_t)r0;
      pk[1] = (bf16_t)r1;
      pk[2] = (bf16_t)r2;
      pk[3] = (bf16_t)r3;
      rsn[nt] = (r0 + r1) + (r2 + r3);
      *(bf16x4*)&pw[l16 * 72 + nt * 16 + quad * 4] = pk;
    }
    float rs = (rsn[0] + rsn[1]) + (rsn[2] + rsn[3]);
    rs += __shfl_xor(rs, 16);
    rs += __shfl_xor(rs, 32);
    lrow += rs;

    // PV: P A-frag read back (wave-private tile; no barrier needed)
    bf16x8 pf0 = *(const bf16x8*)&pw[l16 * 72 + quad * 8];
    bf16x8 pf1 = *(const bf16x8*)&pw[l16 * 72 + 32 + quad * 8];
    __builtin_amdgcn_s_setprio(1);
#pragma unroll
    for (int dt = 0; dt < 4; ++dt) {
      bf16x8 vf0 = *(const bf16x8*)&Vt[(dt * 16 + l16) * 72 + quad * 8];
      bf16x8 vf1 = *(const bf16x8*)&Vt[(dt * 16 + l16) * 72 + 32 + quad * 8];
      Of[dt] = MFMA16(pf0, vf0, Of[dt]);
      Of[dt] = MFMA16(pf1, vf1, Of[dt]);
    }
    __builtin_amdgcn_s_setprio(0);
  }

  // epilogue: broadcast l to row domain, write O over this wave's Q rows
  float lr[4];
#pragma unroll
  for (int r = 0; r < 4; ++r) lr[r] = __shfl(lrow, quad * 4 + r, 16);
  const int t = Q0 + wave * 16 + quad * 4;
#pragma unroll
  for (int r = 0; r < 4; ++r) {
    const float inv = 1.0f / lr[r];
    bf16_t* op = base + (size_t)(t + r) * C3 + h * 64 + l16;
#pragma unroll
    for (int dt = 0; dt < 4; ++dt)
      op[dt * 16] = (bf16_t)(Of[dt][r] * inv);
  }
}

// ---------------------------------------------------------------------------
// I/O contract (R8 probe): ALL inputs f32; output f32.
// ---------------------------------------------------------------------------
extern "C" void kernel_launch(void* const* d_in, const int* in_sizes, int n_in,
                              void* d_out, int out_size, void* d_ws,
                              size_t ws_size, hipStream_t stream) {
  constexpr int B = 4, T = 2048, C = 1024;
  constexpr int M = B * T;  // 8192

  const float* x = (const float*)d_in[0];
  const float* w_qkv = (const float*)d_in[1];
  const float* w_out = (const float*)d_in[2];
  const float* b_out = (const float*)d_in[3];
  for (int i = 0; i < n_in; ++i) {
    const long long s = in_sizes[i];
    if (s == (long long)M * C) x = (const float*)d_in[i];
    else if (s == (long long)3 * C * C) w_qkv = (const float*)d_in[i];
    else if (s == (long long)C * C) w_out = (const float*)d_in[i];
    else if (s == C) b_out = (const float*)d_in[i];
  }

  // bf16 copies of x and w_qkv live in d_out (32 MB): dead before the final
  // GEMM overwrites d_out. ws holds qkv [M,3C] bf16 = 48 MB (proven safe);
  // if ws has 2 MB more, a bf16 copy of w_out lives after qkv so the final
  // GEMM can use the fast global_load_lds path instead of WF32 staging.
  bf16_t* xb = (bf16_t*)d_out;                    // 16 MB
  bf16_t* wqb = xb + (size_t)M * C;               // 6 MB
  bf16_t* qkv = (bf16_t*)d_ws;                    // 48 MB
  bf16_t* wob = qkv + (size_t)M * 3 * C;          // +2 MB (guarded)
  const bool ws_ok =
      ws_size >= (size_t)M * 3 * C * 2 + (size_t)C * C * 2;

  cvt_f32_bf16<<<1024, 256, 0, stream>>>(x, xb, (long long)M * C);
  cvt_f32_bf16<<<512, 256, 0, stream>>>(w_qkv, wqb, 3LL * C * C);
  if (ws_ok)
    cvt_f32_bf16<<<256, 256, 0, stream>>>(w_out, wob, (long long)C * C);

  // fused QKV: [M,3C] = xb @ wqb^T
  gemm_async<false, bf16_t, false>
      <<<dim3(3 * C / 128, M / 128), 256, 0, stream>>>(
          xb, C, wqb, nullptr, qkv, 3 * C, M, 3 * C, C);

  // attention in place (Q slot of qkv); one strip per block, 4 blocks/CU
  attn_mfma<<<dim3(B * 16, 16), 512, 0, stream>>>(qkv);

  // out = att @ w_out^T + b_out -> f32 d_out (overwrites xb/wqb, now dead)
  if (ws_ok)
    gemm_async<false, float, true><<<dim3(C / 128, M / 128), 256, 0, stream>>>(
        qkv, 3 * C, wob, b_out, (float*)d_out, C, M, C, C);
  else
    gemm_async<true, float, true><<<dim3(C / 128, M / 128), 256, 0, stream>>>(
        qkv, 3 * C, w_out, b_out, (float*)d_out, C, M, C, C);
}

// Round 6
// 260.925 us; speedup vs baseline: 1.0218x; 1.0218x over previous
//
#include <hip/hip_runtime.h>
#include <hip/hip_bf16.h>

typedef __bf16 bf16_t;
typedef __bf16 bf16x4 __attribute__((ext_vector_type(4)));
typedef __bf16 bf16x8 __attribute__((ext_vector_type(8)));
typedef float f32x4 __attribute__((ext_vector_type(4)));

#define MFMA16(a, b, c) __builtin_amdgcn_mfma_f32_16x16x32_bf16(a, b, c, 0, 0, 0)

// async 16B global->LDS (m97 pattern). lds ptr wave-uniform; lane writes
// ldsbase + lane*16.
__device__ __forceinline__ void gld16(const bf16_t* g, bf16_t* l) {
  __builtin_amdgcn_global_load_lds(
      (const __attribute__((address_space(1))) unsigned int*)(const void*)g,
      (__attribute__((address_space(3))) unsigned int*)(void*)l, 16, 0, 0);
}

// ---------------------------------------------------------------------------
// f32 -> bf16 elementwise convert (n multiple of 8)
// ---------------------------------------------------------------------------
__global__ __launch_bounds__(256) void cvt_f32_bf16(
    const float* __restrict__ src, bf16_t* __restrict__ dst, long long n) {
  long long i = ((long long)blockIdx.x * 256 + threadIdx.x) * 8;
  const long long stride = (long long)gridDim.x * 256 * 8;
  for (; i < n; i += stride) {
    f32x4 a = *(const f32x4*)(src + i);
    f32x4 b = *(const f32x4*)(src + i + 4);
    bf16x8 r;
#pragma unroll
    for (int e = 0; e < 4; ++e) {
      r[e] = (bf16_t)a[e];
      r[4 + e] = (bf16_t)b[e];
    }
    *(bf16x8*)(dst + i) = r;
  }
}

// ---------------------------------------------------------------------------
// GEMM: C[m][n] = sum_k A[m][k]*W[n][k] (+bias). A bf16 via global_load_lds.
// W: bf16 via global_load_lds (WF32=false) or f32 via reg-staging (true).
// 128x128 tile, 4 waves (2x2), 64x64/wave, BK=32, 2-phase double-buffer,
// __launch_bounds__(256,3).
//
// v6 (this round): L2-resident SUPER-TILE rasterization. Old T1 chunking
// gave each XCD 8 m-rows x full N -> B working set 6 MB > 4 MB L2 -> B
// re-fetched ~8x (≈400 MB of panel traffic). New mapping: 8x8-block
// super-tiles (A 2MB + B 2MB = L2-resident) pinned to one XCD using the
// measured orig%8=XCD dispatch: xcd=orig&7, slot=orig>>3; 64 consecutive
// slots = one super-tile. Bijective when gx%8==0 && gy%8==0 && NST%8==0
// (both our grids); guarded fallback to old mapping otherwise.
// ---------------------------------------------------------------------------
template <bool WF32, typename TC, bool BIAS>
__global__ __launch_bounds__(256, 3) void gemm_async(
    const bf16_t* __restrict__ A, int lda, const void* __restrict__ Wv,
    const float* __restrict__ bias, TC* __restrict__ C, int ldc,
    int M, int N, int K) {
  constexpr int BST = WF32 ? 40 : 32;
  __shared__ bf16_t As[2][128 * 32];   // unpadded: global_load_lds layout
  __shared__ bf16_t Bs[2][128 * BST];

  const int tid = threadIdx.x;
  const int i = tid & 63;
  const int w = tid >> 6;
  const int l16 = tid & 15;
  const int quad = (tid >> 4) & 3;
  const int wm = w & 1;
  const int wn = w >> 1;

  // super-tile / XCD-aware block mapping
  const int gx = gridDim.x, gy = gridDim.y;
  const int orig = blockIdx.y * gx + blockIdx.x;
  int m0, n0;
  const int NSN = gx >> 3, NSM = gy >> 3;
  const int NST = NSN * NSM;
  if ((gx & 7) == 0 && (gy & 7) == 0 && (NST & 7) == 0) {
    const int xcd = orig & 7;
    const int slot = orig >> 3;          // [0, 8*NST)
    const int stpx = NST >> 3;           // super-tiles per XCD
    const int st = xcd * stpx + (slot >> 6);
    const int loc = slot & 63;
    const int sm = st / NSN, sn = st % NSN;
    m0 = (sm * 8 + (loc & 7)) * 128;
    n0 = (sn * 8 + (loc >> 3)) * 128;
  } else {
    const int nwg = gx * gy;
    int wg = orig;
    if ((nwg & 7) == 0) wg = (wg & 7) * (nwg >> 3) + (wg >> 3);
    m0 = (wg / gx) * 128;
    n0 = (wg % gx) * 128;
  }

  const bf16_t* ag = A + (size_t)(m0 + w * 32 + (i >> 2)) * lda + (i & 3) * 8;
  bf16_t* as0[2] = {&As[0][(w * 32) * 32], &As[1][(w * 32) * 32]};
  bf16_t* as1[2] = {&As[0][(w * 32 + 16) * 32], &As[1][(w * 32 + 16) * 32]};

  const bf16_t* bg = nullptr;
  bf16_t *bs0[2] = {nullptr, nullptr}, *bs1[2] = {nullptr, nullptr};
  const float* wfg = nullptr;
  bf16_t* bsw[2] = {nullptr, nullptr};
  if (!WF32) {
    bg = (const bf16_t*)Wv + (size_t)(n0 + w * 32 + (i >> 2)) * K + (i & 3) * 8;
    bs0[0] = &Bs[0][(w * 32) * 32];
    bs0[1] = &Bs[1][(w * 32) * 32];
    bs1[0] = &Bs[0][(w * 32 + 16) * 32];
    bs1[1] = &Bs[1][(w * 32 + 16) * 32];
  } else {
    const int srow = tid >> 1;
    const int scol = (tid & 1) * 16;
    wfg = (const float*)Wv + (size_t)(n0 + srow) * K + scol;
    bsw[0] = &Bs[0][srow * BST + scol];
    bsw[1] = &Bs[1][srow * BST + scol];
  }

  f32x4 acc[4][4] = {};

  // ---- prologue: stage K-tile 0 into buffer 0 ----
  gld16(ag, as0[0]);
  gld16(ag + 16 * lda, as1[0]);
  if (!WF32) {
    gld16(bg, bs0[0]);
    gld16(bg + 16 * K, bs1[0]);
  } else {
    f32x4 a = *(const f32x4*)(wfg);
    f32x4 b = *(const f32x4*)(wfg + 4);
    f32x4 c2 = *(const f32x4*)(wfg + 8);
    f32x4 d = *(const f32x4*)(wfg + 12);
    bf16x8 r0, r1;
#pragma unroll
    for (int e = 0; e < 4; ++e) {
      r0[e] = (bf16_t)a[e];
      r0[4 + e] = (bf16_t)b[e];
      r1[e] = (bf16_t)c2[e];
      r1[4 + e] = (bf16_t)d[e];
    }
    *(bf16x8*)(bsw[0]) = r0;
    *(bf16x8*)(bsw[0] + 8) = r1;
  }
  __syncthreads();  // implicit vmcnt(0): tile 0 resident

  int cur = 0;
  for (int k0 = 0; k0 < K; k0 += 32) {
    const bool has_next = (k0 + 32 < K);
    const int nxt = cur ^ 1;
    f32x4 wa, wb, wc, wd;  // WF32 staging regs (issued early, used late)

    // issue next tile's loads -> other buffer (in flight during compute)
    if (has_next) {
      gld16(ag + k0 + 32, as0[nxt]);
      gld16(ag + 16 * lda + k0 + 32, as1[nxt]);
      if (!WF32) {
        gld16(bg + k0 + 32, bs0[nxt]);
        gld16(bg + 16 * K + k0 + 32, bs1[nxt]);
      } else {
        wa = *(const f32x4*)(wfg + k0 + 32);
        wb = *(const f32x4*)(wfg + k0 + 36);
        wc = *(const f32x4*)(wfg + k0 + 40);
        wd = *(const f32x4*)(wfg + k0 + 44);
      }
    }

    // compute current tile
    bf16x8 af[4], bfr[4];
#pragma unroll
    for (int t = 0; t < 4; ++t) {
      af[t] = *(const bf16x8*)&As[cur][(wm * 64 + t * 16 + l16) * 32 + quad * 8];
      bfr[t] =
          *(const bf16x8*)&Bs[cur][(wn * 64 + t * 16 + l16) * BST + quad * 8];
    }
    __builtin_amdgcn_s_setprio(1);
#pragma unroll
    for (int mi = 0; mi < 4; ++mi)
#pragma unroll
      for (int ni = 0; ni < 4; ++ni)
        acc[mi][ni] = MFMA16(af[mi], bfr[ni], acc[mi][ni]);
    __builtin_amdgcn_s_setprio(0);

    // WF32: convert + commit staged regs (vmcnt waits here, after MFMA)
    if (WF32 && has_next) {
      bf16x8 r0, r1;
#pragma unroll
      for (int e = 0; e < 4; ++e) {
        r0[e] = (bf16_t)wa[e];
        r0[4 + e] = (bf16_t)wb[e];
        r1[e] = (bf16_t)wc[e];
        r1[4 + e] = (bf16_t)wd[e];
      }
      *(bf16x8*)(bsw[nxt]) = r0;
      *(bf16x8*)(bsw[nxt] + 8) = r1;
    }

    __syncthreads();  // drains vmcnt+lgkmcnt; next tile resident, cur free
    cur = nxt;
  }

#pragma unroll
  for (int ni = 0; ni < 4; ++ni) {
    const int col = n0 + wn * 64 + ni * 16 + l16;
    const float bv = BIAS ? bias[col] : 0.0f;
#pragma unroll
    for (int mi = 0; mi < 4; ++mi) {
      const int row = m0 + wm * 64 + mi * 16 + quad * 4;
#pragma unroll
      for (int r = 0; r < 4; ++r)
        C[(size_t)(row + r) * ldc + col] = (TC)(acc[mi][ni][r] + bv);
    }
  }
}

// ---------------------------------------------------------------------------
// Flash attention (causal), qkv interleaved [B*T, 3C] bf16 (q|k|v).
// Output overwrites the Q slot in place (R3-verified disjointness).
//
// REVERTED to the round-2 configuration (best measured: 87.2 µs):
// pairing grid (8, B*H), single-buffered Ks/Vt, 2 barriers/tile.
// v2: swapped QK^T; v3: exp2-domain softmax, diagonal-only mask,
// exact defer-skip, T14 reg-staged prefetch, setprio.
// (r4 dbuf barrier-diet and r5 occupancy were both measured neutral;
// attn is sync/latency-convoy-bound, not slot- or BW-bound.)
// ---------------------------------------------------------------------------
__global__ __launch_bounds__(512, 4) void attn_mfma(bf16_t* __restrict__ qkv) {
  constexpr int T = 2048, C3 = 3072, C = 1024;
  __shared__ bf16_t Ks[64 * 72];      // [token][d], +8 pad
  __shared__ bf16_t Vt[64 * 72];      // [d][token], +8 pad
  __shared__ bf16_t Ps[8 * 16 * 72];  // per-wave P tile [qrow][key]

  const int tid = threadIdx.x;
  const int wave = tid >> 6;        // 0..7
  const int lane = tid & 63;
  const int l16 = tid & 15;
  const int quad = (tid >> 4) & 3;
  const int p = blockIdx.x;         // 0..7 -> strips p and 15-p
  const int b = blockIdx.y >> 4;
  const int h = blockIdx.y & 15;
  bf16_t* base = qkv + (size_t)b * T * C3;

  // 1/sqrt(64) * log2(e): softmax entirely in exp2 domain.
  const float QSCALE = 0.125f * 1.44269504088896340736f;

  // K staging map (waves 0-3): token = tid>>2 (0..63), 16 d's at (tid&3)*16
  const int kst = tid >> 2;
  const int ksd = (tid & 3) * 16;
  // V staging map (waves 4-7): token = lane, 16 d's at (wave-4)*16
  const int vtok = lane;
  const int vdg = (wave - 4) * 16;

  bf16_t* pw = &Ps[wave * 16 * 72];

  bf16x8 st0, st1;  // staging regs: K halves (waves 0-3) or V halves (4-7)

  for (int s = 0; s < 2; ++s) {
    const int qt = (s == 0) ? p : 15 - p;
    const int Q0 = qt * 128;
    const int qlo = Q0 + wave * 16;
    const int jmax = Q0 + 64;

    // Q fragments, prescaled by 0.125*log2e (one extra bf16 rounding on Q)
    bf16x8 qf[2];
    {
      const bf16_t* qp = base + (size_t)(qlo + l16) * C3 + h * 64 + quad * 8;
      bf16x8 a = *(const bf16x8*)qp;
      bf16x8 c = *(const bf16x8*)(qp + 32);
#pragma unroll
      for (int e = 0; e < 8; ++e) {
        a[e] = (bf16_t)((float)a[e] * QSCALE);
        c[e] = (bf16_t)((float)c[e] * QSCALE);
      }
      qf[0] = a;
      qf[1] = c;
    }

    f32x4 Of[4] = {};
    float mrow = -1e30f;
    float lrow = 0.f;

    // prologue: issue tile-0 loads into regs (T14 split)
    if (wave < 4) {
      const bf16_t* kp = base + (size_t)kst * C3 + C + h * 64 + ksd;
      st0 = *(const bf16x8*)kp;
      st1 = *(const bf16x8*)(kp + 8);
    } else {
      const bf16_t* vp = base + (size_t)vtok * C3 + 2 * C + h * 64 + vdg;
      st0 = *(const bf16x8*)vp;
      st1 = *(const bf16x8*)(vp + 8);
    }

    for (int j0 = 0; j0 <= jmax; j0 += 64) {
      __syncthreads();  // previous tile's Ks/Vt readers are done
      // commit staged regs -> LDS (implicit vmcnt wait on st0/st1)
      if (wave < 4) {
        *(bf16x8*)&Ks[kst * 72 + ksd] = st0;
        *(bf16x8*)&Ks[kst * 72 + ksd + 8] = st1;
      } else {
#pragma unroll
        for (int e = 0; e < 8; ++e) {
          Vt[(vdg + e) * 72 + vtok] = st0[e];
          Vt[(vdg + 8 + e) * 72 + vtok] = st1[e];
        }
      }
      // issue next tile's loads; latency hides under compute below
      if (j0 + 64 <= jmax) {
        const int jn = j0 + 64;
        if (wave < 4) {
          const bf16_t* kp = base + (size_t)(jn + kst) * C3 + C + h * 64 + ksd;
          st0 = *(const bf16x8*)kp;
          st1 = *(const bf16x8*)(kp + 8);
        } else {
          const bf16_t* vp =
              base + (size_t)(jn + vtok) * C3 + 2 * C + h * 64 + vdg;
          st0 = *(const bf16x8*)vp;
          st1 = *(const bf16x8*)(vp + 8);
        }
      }
      __syncthreads();

      if (qlo + 15 < j0) continue;  // wave-uniform: fully-masked wave skips

      // S^T tile: lane holds S[qlo+l16][j0 + nt*16 + quad*4 + r]
      float Sv[4][4];
      const int qrow = qlo + l16;
      __builtin_amdgcn_s_setprio(1);
#pragma unroll
      for (int nt = 0; nt < 4; ++nt) {
        f32x4 sacc = {};
#pragma unroll
        for (int s2 = 0; s2 < 2; ++s2) {
          bf16x8 kf =
              *(const bf16x8*)&Ks[(nt * 16 + l16) * 72 + s2 * 32 + quad * 8];
          sacc = MFMA16(kf, qf[s2], sacc);  // swapped: rows=keys, cols=qrows
        }
#pragma unroll
        for (int r = 0; r < 4; ++r) Sv[nt][r] = sacc[r];
      }
      __builtin_amdgcn_s_setprio(0);

      // causal mask: only the diagonal-overlap tile needs it (wave-uniform)
      if (j0 + 64 > qlo) {
#pragma unroll
        for (int nt = 0; nt < 4; ++nt) {
          const int keyb = j0 + nt * 16 + quad * 4;
#pragma unroll
          for (int r = 0; r < 4; ++r)
            if (keyb + r > qrow) Sv[nt][r] = -1e30f;
        }
      }

      // tile max for this lane's row (tree, then cross-quad)
      float vm[4];
#pragma unroll
      for (int nt = 0; nt < 4; ++nt)
        vm[nt] = fmaxf(fmaxf(Sv[nt][0], Sv[nt][1]),
                       fmaxf(Sv[nt][2], Sv[nt][3]));
      float v = fmaxf(fmaxf(vm[0], vm[1]), fmaxf(vm[2], vm[3]));
      v = fmaxf(v, __shfl_xor(v, 16));
      v = fmaxf(v, __shfl_xor(v, 32));

      // exact defer-skip: when no row grew, alpha==1 exactly -> skip rescale
      if (__any(v > mrow)) {
        const float mnew = fmaxf(mrow, v);
        const float alpha = __builtin_amdgcn_exp2f(mrow - mnew);
        mrow = mnew;
        lrow *= alpha;
        float ar[4];
#pragma unroll
        for (int r = 0; r < 4; ++r) ar[r] = __shfl(alpha, quad * 4 + r, 16);
#pragma unroll
        for (int dt = 0; dt < 4; ++dt)
#pragma unroll
          for (int r = 0; r < 4; ++r) Of[dt][r] *= ar[r];
      }

      // P = exp2(S - m); pack 4 consecutive keys -> one ds_write_b64 per nt
      float rsn[4];
#pragma unroll
      for (int nt = 0; nt < 4; ++nt) {
        bf16x4 pk;
        float r0 = __builtin_amdgcn_exp2f(Sv[nt][0] - mrow);
        float r1 = __builtin_amdgcn_exp2f(Sv[nt][1] - mrow);
        float r2 = __builtin_amdgcn_exp2f(Sv[nt][2] - mrow);
        float r3 = __builtin_amdgcn_exp2f(Sv[nt][3] - mrow);
        pk[0] = (bf16_t)r0;
        pk[1] = (bf16_t)r1;
        pk[2] = (bf16_t)r2;
        pk[3] = (bf16_t)r3;
        rsn[nt] = (r0 + r1) + (r2 + r3);
        *(bf16x4*)&pw[l16 * 72 + nt * 16 + quad * 4] = pk;
      }
      float rs = (rsn[0] + rsn[1]) + (rsn[2] + rsn[3]);
      rs += __shfl_xor(rs, 16);
      rs += __shfl_xor(rs, 32);
      lrow += rs;

      // PV: P A-frag read back (wave-private tile; no barrier needed)
      bf16x8 pf0 = *(const bf16x8*)&pw[l16 * 72 + quad * 8];
      bf16x8 pf1 = *(const bf16x8*)&pw[l16 * 72 + 32 + quad * 8];
      __builtin_amdgcn_s_setprio(1);
#pragma unroll
      for (int dt = 0; dt < 4; ++dt) {
        bf16x8 vf0 = *(const bf16x8*)&Vt[(dt * 16 + l16) * 72 + quad * 8];
        bf16x8 vf1 = *(const bf16x8*)&Vt[(dt * 16 + l16) * 72 + 32 + quad * 8];
        Of[dt] = MFMA16(pf0, vf0, Of[dt]);
        Of[dt] = MFMA16(pf1, vf1, Of[dt]);
      }
      __builtin_amdgcn_s_setprio(0);
    }

    // epilogue: broadcast l to row domain, write O over this wave's Q rows
    float lr[4];
#pragma unroll
    for (int r = 0; r < 4; ++r) lr[r] = __shfl(lrow, quad * 4 + r, 16);
    const int t = Q0 + wave * 16 + quad * 4;
#pragma unroll
    for (int r = 0; r < 4; ++r) {
      const float inv = 1.0f / lr[r];
      bf16_t* op = base + (size_t)(t + r) * C3 + h * 64 + l16;
#pragma unroll
      for (int dt = 0; dt < 4; ++dt)
        op[dt * 16] = (bf16_t)(Of[dt][r] * inv);
    }
  }
}

// ---------------------------------------------------------------------------
// I/O contract (R8 probe): ALL inputs f32; output f32.
// ---------------------------------------------------------------------------
extern "C" void kernel_launch(void* const* d_in, const int* in_sizes, int n_in,
                              void* d_out, int out_size, void* d_ws,
                              size_t ws_size, hipStream_t stream) {
  constexpr int B = 4, T = 2048, C = 1024;
  constexpr int M = B * T;  // 8192

  const float* x = (const float*)d_in[0];
  const float* w_qkv = (const float*)d_in[1];
  const float* w_out = (const float*)d_in[2];
  const float* b_out = (const float*)d_in[3];
  for (int i = 0; i < n_in; ++i) {
    const long long s = in_sizes[i];
    if (s == (long long)M * C) x = (const float*)d_in[i];
    else if (s == (long long)3 * C * C) w_qkv = (const float*)d_in[i];
    else if (s == (long long)C * C) w_out = (const float*)d_in[i];
    else if (s == C) b_out = (const float*)d_in[i];
  }

  // bf16 copies of x and w_qkv live in d_out (32 MB): dead before the final
  // GEMM overwrites d_out. ws holds qkv [M,3C] bf16 = 48 MB (proven safe);
  // if ws has 2 MB more, a bf16 copy of w_out lives after qkv so the final
  // GEMM can use the fast global_load_lds path instead of WF32 staging.
  bf16_t* xb = (bf16_t*)d_out;                    // 16 MB
  bf16_t* wqb = xb + (size_t)M * C;               // 6 MB
  bf16_t* qkv = (bf16_t*)d_ws;                    // 48 MB
  bf16_t* wob = qkv + (size_t)M * 3 * C;          // +2 MB (guarded)
  const bool ws_ok =
      ws_size >= (size_t)M * 3 * C * 2 + (size_t)C * C * 2;

  cvt_f32_bf16<<<1024, 256, 0, stream>>>(x, xb, (long long)M * C);
  cvt_f32_bf16<<<512, 256, 0, stream>>>(w_qkv, wqb, 3LL * C * C);
  if (ws_ok)
    cvt_f32_bf16<<<256, 256, 0, stream>>>(w_out, wob, (long long)C * C);

  // fused QKV: [M,3C] = xb @ wqb^T
  gemm_async<false, bf16_t, false>
      <<<dim3(3 * C / 128, M / 128), 256, 0, stream>>>(
          xb, C, wqb, nullptr, qkv, 3 * C, M, 3 * C, C);

  // attention in place (Q slot of qkv); work-balanced pairing grid
  attn_mfma<<<dim3(8, B * 16), 512, 0, stream>>>(qkv);

  // out = att @ w_out^T + b_out -> f32 d_out (overwrites xb/wqb, now dead)
  if (ws_ok)
    gemm_async<false, float, true><<<dim3(C / 128, M / 128), 256, 0, stream>>>(
        qkv, 3 * C, wob, b_out, (float*)d_out, C, M, C, C);
  else
    gemm_async<true, float, true><<<dim3(C / 128, M / 128), 256, 0, stream>>>(
        qkv, 3 * C, w_out, b_out, (float*)d_out, C, M, C, C);
}